// Round 1
// baseline (360.672 us; speedup 1.0000x reference)
//
#include <hip/hip_runtime.h>

// Problem constants
// B=16, C=256, L=1024, H=8, DK=64, HD=512
#define EPS 1e-5f
#define SLOPE 0.01f

#define BM 64
#define BN 128
#define BKK 16

// Generic batched row-major SGEMM: C[z] = A[z] * B[z]
// A: [M,K] lda=K, B: [K,N] ldb=N, C: [M,N] ldc=N. M%64==0, N%128==0, K%16==0.
// 256 threads, each computes 4(m) x 8(n) split as two 4-col fragments 64 apart
// (avoids 4-way LDS bank conflict of a contiguous 8-wide fragment).
__global__ __launch_bounds__(256) void sgemm_kernel(
    const float* __restrict__ A, const float* __restrict__ B,
    float* __restrict__ C, int M, int N, int K,
    long long sA, long long sB, long long sC)
{
    const int z = blockIdx.z;
    A += (size_t)z * sA;
    B += (size_t)z * sB;
    C += (size_t)z * sC;
    const int m0 = blockIdx.x * BM;
    const int n0 = blockIdx.y * BN;
    const int tid = threadIdx.x;
    const int tx = tid & 15;   // n-group
    const int ty = tid >> 4;   // m-group

    __shared__ float As[BKK][BM];   // transposed: As[k][m]
    __shared__ float Bs[BKK][BN];

    float acc[4][8];
    #pragma unroll
    for (int i = 0; i < 4; i++)
        #pragma unroll
        for (int j = 0; j < 8; j++) acc[i][j] = 0.f;

    const int a_row = tid >> 2;          // 0..63
    const int a_kc  = (tid & 3) << 2;    // 0,4,8,12
    const int b_kr  = tid >> 4;          // 0..15
    const int b_nc  = (tid & 15) << 3;   // 0..120

    for (int k0 = 0; k0 < K; k0 += BKK) {
        float4 av  = *(const float4*)(A + (size_t)(m0 + a_row) * K + k0 + a_kc);
        const float* bp = B + (size_t)(k0 + b_kr) * N + n0 + b_nc;
        float4 bv0 = *(const float4*)(bp);
        float4 bv1 = *(const float4*)(bp + 4);

        __syncthreads();   // previous iteration's compute done before overwrite
        As[a_kc + 0][a_row] = av.x;
        As[a_kc + 1][a_row] = av.y;
        As[a_kc + 2][a_row] = av.z;
        As[a_kc + 3][a_row] = av.w;
        *(float4*)&Bs[b_kr][b_nc]     = bv0;
        *(float4*)&Bs[b_kr][b_nc + 4] = bv1;
        __syncthreads();

        #pragma unroll
        for (int k = 0; k < BKK; ++k) {
            float4 a  = *(const float4*)&As[k][ty << 2];
            float4 b0 = *(const float4*)&Bs[k][tx << 2];        // cols tx*4..+3
            float4 b1 = *(const float4*)&Bs[k][64 + (tx << 2)]; // cols 64+tx*4..+3
            float am[4] = {a.x, a.y, a.z, a.w};
            float bn[8] = {b0.x, b0.y, b0.z, b0.w, b1.x, b1.y, b1.z, b1.w};
            #pragma unroll
            for (int i = 0; i < 4; i++)
                #pragma unroll
                for (int j = 0; j < 8; j++)
                    acc[i][j] += am[i] * bn[j];
        }
    }

    #pragma unroll
    for (int i = 0; i < 4; i++) {
        float* crow = C + (size_t)(m0 + (ty << 2) + i) * N + n0;
        float4 r0 = {acc[i][0], acc[i][1], acc[i][2], acc[i][3]};
        float4 r1 = {acc[i][4], acc[i][5], acc[i][6], acc[i][7]};
        *(float4*)(crow + (tx << 2))      = r0;
        *(float4*)(crow + 64 + (tx << 2)) = r1;
    }
}

// Stage B: Tpart[lc][bh][d][e] = sum_{l in chunk lc} V[b,h*64+d,l] * K[b,h*64+e,l]
// grid (4 lchunks, 128 bh), 256 threads, 4x4 per thread over 64x64 output.
__global__ __launch_bounds__(256) void kvT_kernel(
    const float* __restrict__ Kp, const float* __restrict__ Vp,
    float* __restrict__ Tpart)
{
    const int lc = blockIdx.x;   // 0..3
    const int bh = blockIdx.y;   // 0..127
    const int b = bh >> 3, h = bh & 7;
    const float* Kh = Kp + ((size_t)b * 512 + (size_t)h * 64) * 1024;
    const float* Vh = Vp + ((size_t)b * 512 + (size_t)h * 64) * 1024;
    float* out = Tpart + ((size_t)lc * 128 + bh) * 4096;

    const int tid = threadIdx.x;
    const int tx = tid & 15;    // e-group (K rows)
    const int ty = tid >> 4;    // d-group (V rows)

    __shared__ float Kt[64][33];
    __shared__ float Vt[64][33];

    float acc[4][4];
    #pragma unroll
    for (int i = 0; i < 4; i++)
        #pragma unroll
        for (int j = 0; j < 4; j++) acc[i][j] = 0.f;

    const int lr_row = tid >> 2;          // 0..63
    const int lr_col = (tid & 3) << 3;    // 0,8,16,24

    const int l0base = lc * 256;
    for (int l0 = l0base; l0 < l0base + 256; l0 += 32) {
        const float* kp = Kh + (size_t)lr_row * 1024 + l0 + lr_col;
        const float* vp = Vh + (size_t)lr_row * 1024 + l0 + lr_col;
        float4 k0v = *(const float4*)(kp);
        float4 k1v = *(const float4*)(kp + 4);
        float4 v0v = *(const float4*)(vp);
        float4 v1v = *(const float4*)(vp + 4);

        __syncthreads();
        Kt[lr_row][lr_col + 0] = k0v.x; Kt[lr_row][lr_col + 1] = k0v.y;
        Kt[lr_row][lr_col + 2] = k0v.z; Kt[lr_row][lr_col + 3] = k0v.w;
        Kt[lr_row][lr_col + 4] = k1v.x; Kt[lr_row][lr_col + 5] = k1v.y;
        Kt[lr_row][lr_col + 6] = k1v.z; Kt[lr_row][lr_col + 7] = k1v.w;
        Vt[lr_row][lr_col + 0] = v0v.x; Vt[lr_row][lr_col + 1] = v0v.y;
        Vt[lr_row][lr_col + 2] = v0v.z; Vt[lr_row][lr_col + 3] = v0v.w;
        Vt[lr_row][lr_col + 4] = v1v.x; Vt[lr_row][lr_col + 5] = v1v.y;
        Vt[lr_row][lr_col + 6] = v1v.z; Vt[lr_row][lr_col + 7] = v1v.w;
        __syncthreads();

        #pragma unroll
        for (int l = 0; l < 32; ++l) {
            float vm[4], ke[4];
            #pragma unroll
            for (int i = 0; i < 4; i++) vm[i] = Vt[(ty << 2) + i][l];
            #pragma unroll
            for (int j = 0; j < 4; j++) ke[j] = Kt[(tx << 2) + j][l];
            #pragma unroll
            for (int i = 0; i < 4; i++)
                #pragma unroll
                for (int j = 0; j < 4; j++)
                    acc[i][j] += vm[i] * ke[j];
        }
    }

    #pragma unroll
    for (int i = 0; i < 4; i++)
        #pragma unroll
        for (int j = 0; j < 4; j++)
            out[(size_t)((ty << 2) + i) * 64 + (tx << 2) + j] = acc[i][j];
}

// Reduce 4 l-chunk partials and apply 1/DK scale. 524288 outputs.
__global__ __launch_bounds__(256) void reduceT_kernel(
    const float* __restrict__ Tpart, float* __restrict__ T)
{
    const size_t S = 524288;
    size_t i = ((size_t)blockIdx.x * 256 + threadIdx.x) * 4;
    float4 a = *(const float4*)(Tpart + i);
    float4 b = *(const float4*)(Tpart + S + i);
    float4 c = *(const float4*)(Tpart + 2 * S + i);
    float4 d = *(const float4*)(Tpart + 3 * S + i);
    float4 r;
    const float s = 1.0f / 64.0f;
    r.x = (a.x + b.x + c.x + d.x) * s;
    r.y = (a.y + b.y + c.y + d.y) * s;
    r.z = (a.z + b.z + c.z + d.z) * s;
    r.w = (a.w + b.w + c.w + d.w) * s;
    *(float4*)(T + i) = r;
}

// InstanceNorm over L + gamma residual + LeakyReLU.
// grid 4096 rows (b*256+c), 256 threads, 4 elems (1 float4) per thread.
__global__ __launch_bounds__(256) void norm_kernel(
    const float* __restrict__ o, const float* __restrict__ x,
    const float* __restrict__ gamma, float* __restrict__ y)
{
    const size_t row = blockIdx.x;
    const float* orow = o + row * 1024;
    const float* xrow = x + row * 1024;
    float* yrow = y + row * 1024;
    const int tid = threadIdx.x;

    float4 v = ((const float4*)orow)[tid];
    float s  = v.x + v.y + v.z + v.w;
    float ss = v.x * v.x + v.y * v.y + v.z * v.z + v.w * v.w;
    #pragma unroll
    for (int off = 32; off > 0; off >>= 1) {
        s  += __shfl_down(s, off);
        ss += __shfl_down(ss, off);
    }
    __shared__ float red[10];
    const int wave = tid >> 6, lane = tid & 63;
    if (lane == 0) { red[wave] = s; red[4 + wave] = ss; }
    __syncthreads();
    if (tid == 0) {
        float a  = red[0] + red[1] + red[2] + red[3];
        float b2 = red[4] + red[5] + red[6] + red[7];
        float mu = a * (1.0f / 1024.0f);
        float var = b2 * (1.0f / 1024.0f) - mu * mu;
        red[8] = mu;
        red[9] = rsqrtf(var + EPS);
    }
    __syncthreads();
    const float mu = red[8], inv = red[9], g = gamma[0];
    float4 xv = ((const float4*)xrow)[tid];
    float4 r;
    r.x = (v.x - mu) * inv * g + xv.x;
    r.y = (v.y - mu) * inv * g + xv.y;
    r.z = (v.z - mu) * inv * g + xv.z;
    r.w = (v.w - mu) * inv * g + xv.w;
    r.x = r.x >= 0.f ? r.x : SLOPE * r.x;
    r.y = r.y >= 0.f ? r.y : SLOPE * r.y;
    r.z = r.z >= 0.f ? r.z : SLOPE * r.z;
    r.w = r.w >= 0.f ? r.w : SLOPE * r.w;
    ((float4*)yrow)[tid] = r;
}

extern "C" void kernel_launch(void* const* d_in, const int* in_sizes, int n_in,
                              void* d_out, int out_size, void* d_ws, size_t ws_size,
                              hipStream_t stream) {
    const float* x     = (const float*)d_in[0];   // [16,256,1024]
    const float* Wq    = (const float*)d_in[1];   // [512,256]
    const float* Wk    = (const float*)d_in[2];
    const float* Wv    = (const float*)d_in[3];
    const float* Wo    = (const float*)d_in[4];   // [256,512]
    const float* gamma = (const float*)d_in[5];   // [1]
    float* y = (float*)d_out;                     // [16,256,1024]

    float* ws = (float*)d_ws;
    float* Q     = ws;                    // 16*512*1024 = 8388608 floats
    float* Kp    = ws + 8388608;          // 8388608
    float* V     = ws + 16777216;         // 8388608
    float* Tpart = ws + 25165824;         // 4*128*4096 = 2097152
    float* T     = ws + 27262976;         // 128*4096 = 524288
    float* merged = Kp;   // reuse: K consumed after kvT
    float* o      = V;    // reuse: V consumed after kvT

    dim3 blk(256);

    // QKV projections: [512,256] x [256,1024] per batch
    sgemm_kernel<<<dim3(8, 8, 16), blk, 0, stream>>>(Wq, x, Q,  512, 1024, 256, 0, 262144, 524288);
    sgemm_kernel<<<dim3(8, 8, 16), blk, 0, stream>>>(Wk, x, Kp, 512, 1024, 256, 0, 262144, 524288);
    sgemm_kernel<<<dim3(8, 8, 16), blk, 0, stream>>>(Wv, x, V,  512, 1024, 256, 0, 262144, 524288);

    // T = V K^T / 64 per (b,h), split over 4 l-chunks then reduced
    kvT_kernel<<<dim3(4, 128), blk, 0, stream>>>(Kp, V, Tpart);
    reduceT_kernel<<<dim3(512), blk, 0, stream>>>(Tpart, T);

    // merged_h = T Q_h : [64,64] x [64,1024] per (b,h) -> z = b*8+h
    sgemm_kernel<<<dim3(1, 8, 128), blk, 0, stream>>>(T, Q, merged, 64, 1024, 64, 4096, 65536, 65536);

    // o = Wo merged : [256,512] x [512,1024] per batch
    sgemm_kernel<<<dim3(4, 8, 16), blk, 0, stream>>>(Wo, merged, o, 256, 1024, 512, 0, 524288, 262144);

    // InstanceNorm + gamma residual + LeakyReLU
    norm_kernel<<<dim3(4096), blk, 0, stream>>>(o, x, gamma, y);
}

// Round 2
// 152.649 us; speedup vs baseline: 2.3628x; 2.3628x over previous
//
#include <hip/hip_runtime.h>

typedef __bf16 bf16;
typedef bf16 bf16x8 __attribute__((ext_vector_type(8)));
typedef bf16 bf16x4 __attribute__((ext_vector_type(4)));
typedef float f32x4 __attribute__((ext_vector_type(4)));

#define EPS 1e-5f
#define SLOPE 0.01f

// async global->LDS, 16B per lane. LDS dest is wave-uniform base + lane*16:
// every call site arranges lds offset == (stage_chunk*4096 + wave*1024 + lane*16).
__device__ __forceinline__ void gld_lds16(const bf16* g, bf16* l) {
    __builtin_amdgcn_global_load_lds(
        (const __attribute__((address_space(1))) unsigned int*)g,
        (__attribute__((address_space(3))) unsigned int*)l, 16, 0, 0);
}

// ---------------- prep: x[b][c][l] f32 -> xT[b][l][c] bf16 -------------------
__global__ __launch_bounds__(256) void prep_x(const float* __restrict__ x,
                                              bf16* __restrict__ xT)
{
    __shared__ float tile[64][65];
    const int lt = blockIdx.x;   // l-tile 0..15
    const int ct = blockIdx.y;   // c-tile 0..3
    const int b  = blockIdx.z;
    const int t  = threadIdx.x;
    {
        const int cl = t >> 2;            // 0..63
        const int l4 = (t & 3) << 4;      // 0,16,32,48
        const float* src = x + ((size_t)(b * 256 + ct * 64 + cl)) * 1024 + lt * 64 + l4;
        float4 v0 = ((const float4*)src)[0];
        float4 v1 = ((const float4*)src)[1];
        float4 v2 = ((const float4*)src)[2];
        float4 v3 = ((const float4*)src)[3];
        float* tr = &tile[cl][l4];
        tr[0]=v0.x; tr[1]=v0.y; tr[2]=v0.z; tr[3]=v0.w;
        tr[4]=v1.x; tr[5]=v1.y; tr[6]=v1.z; tr[7]=v1.w;
        tr[8]=v2.x; tr[9]=v2.y; tr[10]=v2.z; tr[11]=v2.w;
        tr[12]=v3.x; tr[13]=v3.y; tr[14]=v3.z; tr[15]=v3.w;
    }
    __syncthreads();
    {
        const int lw = t >> 2;            // 0..63 (l within tile)
        const int ec = (t & 3) << 4;      // 0,16,32,48 (c within tile)
        bf16x8 o0, o1;
        #pragma unroll
        for (int ii = 0; ii < 8; ++ii) {
            o0[ii] = (bf16)tile[ec + ii][lw];
            o1[ii] = (bf16)tile[ec + 8 + ii][lw];
        }
        bf16* dst = xT + ((size_t)(b * 1024 + lt * 64 + lw)) * 256 + ct * 64 + ec;
        *(bf16x8*)dst = o0;
        *(bf16x8*)(dst + 8) = o1;
    }
}

// ------------- prep: pack Wq|Wk|Wv -> Wqkv bf16, Wo -> bf16 ------------------
__global__ __launch_bounds__(256) void prep_w(const float* __restrict__ Wq,
                                              const float* __restrict__ Wk,
                                              const float* __restrict__ Wv,
                                              const float* __restrict__ Wo,
                                              bf16* __restrict__ Wqkv,
                                              bf16* __restrict__ WoB)
{
    const int i = (blockIdx.x * 256 + threadIdx.x) * 4;   // 0..524284
    const float* src;
    bf16* dst;
    if (i < 393216) {
        const int seg = i >> 17;            // 0,1,2
        const int off = i & 131071;
        src = (seg == 0 ? Wq : (seg == 1 ? Wk : Wv)) + off;
        dst = Wqkv + i;
    } else {
        src = Wo + (i - 393216);
        dst = WoB + (i - 393216);
    }
    float4 v = *(const float4*)src;
    bf16x4 o;
    o[0] = (bf16)v.x; o[1] = (bf16)v.y; o[2] = (bf16)v.z; o[3] = (bf16)v.w;
    *(bf16x4*)dst = o;
}

// ------- 128x128-tile MFMA GEMM, B^T form: C[z] = A * Bt[z]^T ---------------
// A [M,KDIM] row-major (shared over z), Bt [N,KDIM] row-major, C [M,N].
template<int KDIM, typename OutT>
__global__ __launch_bounds__(256) void gemm128_bt(
    const bf16* __restrict__ A, const bf16* __restrict__ Bt, OutT* __restrict__ C,
    long long sBt, long long sC, int ldC)
{
    __shared__ bf16 As[128 * 32];
    __shared__ bf16 Bs[128 * 32];
    const int z = blockIdx.z;
    Bt += (size_t)z * sBt;
    C  += (size_t)z * sC;
    const int m0 = blockIdx.x * 128;
    const int n0 = blockIdx.y * 128;
    const int t = threadIdx.x, w = t >> 6, l = t & 63;
    const int srow = w * 16 + (l >> 2);     // staging row (within 64-row half)
    const int ske  = (l & 3) * 8;           // staging k element offset
    const bf16* ga = A  + (size_t)(m0 + srow) * KDIM + ske;
    const bf16* gb = Bt + (size_t)(n0 + srow) * KDIM + ske;
    bf16* la = As + srow * 32 + ske;
    bf16* lb = Bs + srow * 32 + ske;

    const int lm = l & 15, lq = l >> 4;
    const int wm = (w & 1) * 64, wn = (w >> 1) * 64;

    f32x4 acc[4][4] = {};
    for (int kt = 0; kt < KDIM / 32; ++kt) {
        const int k0 = kt * 32;
        gld_lds16(ga + k0, la);
        gld_lds16(ga + k0 + (size_t)64 * KDIM, la + 64 * 32);
        gld_lds16(gb + k0, lb);
        gld_lds16(gb + k0 + (size_t)64 * KDIM, lb + 64 * 32);
        __syncthreads();
        bf16x8 af[4], bfr[4];
        #pragma unroll
        for (int i = 0; i < 4; ++i)
            af[i] = *(const bf16x8*)(As + (wm + i * 16 + lm) * 32 + lq * 8);
        #pragma unroll
        for (int j = 0; j < 4; ++j)
            bfr[j] = *(const bf16x8*)(Bs + (wn + j * 16 + lm) * 32 + lq * 8);
        #pragma unroll
        for (int i = 0; i < 4; ++i)
            #pragma unroll
            for (int j = 0; j < 4; ++j)
                acc[i][j] = __builtin_amdgcn_mfma_f32_16x16x32_bf16(af[i], bfr[j], acc[i][j], 0, 0, 0);
        __syncthreads();
    }
    #pragma unroll
    for (int i = 0; i < 4; ++i)
        #pragma unroll
        for (int j = 0; j < 4; ++j) {
            const int row = m0 + wm + i * 16 + lq * 4;
            const int col = n0 + wn + j * 16 + lm;
            OutT* cp = C + (size_t)row * ldC + col;
            #pragma unroll
            for (int r = 0; r < 4; ++r)
                cp[(size_t)r * ldC] = (OutT)acc[i][j][r];
        }
}

// ---------- transpose Q heads: QKV rows [h*64+e][l] -> Qt[bh][l][e] ----------
__global__ __launch_bounds__(256) void transpose_q(const bf16* __restrict__ QKV,
                                                   bf16* __restrict__ Qt)
{
    __shared__ bf16 tile[64][72];
    const int lt = blockIdx.x;   // 0..15
    const int bh = blockIdx.y;   // 0..127
    const int b = bh >> 3, h = bh & 7;
    const int t = threadIdx.x;
    {
        const int e  = t >> 2;
        const int l4 = (t & 3) << 4;
        const bf16* src = QKV + (size_t)(b * 1536 + h * 64 + e) * 1024 + lt * 64 + l4;
        *(bf16x8*)&tile[e][l4]     = *(const bf16x8*)src;
        *(bf16x8*)&tile[e][l4 + 8] = *(const bf16x8*)(src + 8);
    }
    __syncthreads();
    {
        const int lw = t >> 2;
        const int ec = (t & 3) << 4;
        bf16x8 o0, o1;
        #pragma unroll
        for (int ii = 0; ii < 8; ++ii) {
            o0[ii] = tile[ec + ii][lw];
            o1[ii] = tile[ec + 8 + ii][lw];
        }
        bf16* dst = Qt + (size_t)bh * 65536 + (size_t)(lt * 64 + lw) * 64 + ec;
        *(bf16x8*)dst = o0;
        *(bf16x8*)(dst + 8) = o1;
    }
}

// ------ kvT: T[bh][d][e] = (1/64) sum_l V[d,l]*K[e,l]  (M=N=64, K=1024) ------
__global__ __launch_bounds__(256) void gemm_kvt(const bf16* __restrict__ QKV,
                                                bf16* __restrict__ T)
{
    __shared__ bf16 As[64 * 64];
    __shared__ bf16 Bs[64 * 64];
    const int bh = blockIdx.x;
    const int b = bh >> 3, h = bh & 7;
    const bf16* Ab = QKV + (size_t)(b * 1536 + 1024 + h * 64) * 1024;  // V rows
    const bf16* Bb = QKV + (size_t)(b * 1536 + 512  + h * 64) * 1024;  // K rows
    const int t = threadIdx.x, w = t >> 6, l = t & 63;
    const int srow = w * 8 + (l >> 3);  // 0..31 (+32 for chunk 1)
    const int skq  = l & 7;             // k-quad slot
    const int lm = l & 15, lq = l >> 4;
    const int wm = (w & 1) * 32, wn = (w >> 1) * 32;

    f32x4 acc[2][2] = {};
    for (int kt = 0; kt < 16; ++kt) {
        const int k0 = kt * 64;
        #pragma unroll
        for (int c = 0; c < 2; ++c) {
            const int row = c * 32 + srow;
            const int gq = (skq ^ (row & 7)) * 8;   // XOR swizzle breaks 128B-stride conflicts
            gld_lds16(Ab + (size_t)row * 1024 + k0 + gq, As + row * 64 + skq * 8);
            gld_lds16(Bb + (size_t)row * 1024 + k0 + gq, Bs + row * 64 + skq * 8);
        }
        __syncthreads();
        #pragma unroll
        for (int ks = 0; ks < 2; ++ks) {
            bf16x8 af[2], bfr[2];
            #pragma unroll
            for (int i = 0; i < 2; ++i) {
                const int row = wm + i * 16 + lm;
                const int qg = ks * 4 + lq;
                af[i] = *(const bf16x8*)(As + row * 64 + (qg ^ (row & 7)) * 8);
            }
            #pragma unroll
            for (int j = 0; j < 2; ++j) {
                const int row = wn + j * 16 + lm;
                const int qg = ks * 4 + lq;
                bfr[j] = *(const bf16x8*)(Bs + row * 64 + (qg ^ (row & 7)) * 8);
            }
            #pragma unroll
            for (int i = 0; i < 2; ++i)
                #pragma unroll
                for (int j = 0; j < 2; ++j)
                    acc[i][j] = __builtin_amdgcn_mfma_f32_16x16x32_bf16(af[i], bfr[j], acc[i][j], 0, 0, 0);
        }
        __syncthreads();
    }
    #pragma unroll
    for (int i = 0; i < 2; ++i)
        #pragma unroll
        for (int j = 0; j < 2; ++j)
            #pragma unroll
            for (int r = 0; r < 4; ++r)
                T[(size_t)bh * 4096 + (size_t)(wm + i * 16 + lq * 4 + r) * 64 + wn + j * 16 + lm] =
                    (bf16)(acc[i][j][r] * 0.015625f);
}

// -- mergedT[b][l][h*64+d] = sum_e Qt[bh][l][e] * T[bh][d][e]  (M=1024,N=64,K=64)
__global__ __launch_bounds__(256) void gemm_merged(const bf16* __restrict__ Qt,
                                                   const bf16* __restrict__ T,
                                                   bf16* __restrict__ mergedT)
{
    __shared__ bf16 As[128 * 64];
    __shared__ bf16 Bs[64 * 64];
    const int mt = blockIdx.x;   // 0..7
    const int bh = blockIdx.y;   // 0..127
    const int b = bh >> 3, h = bh & 7;
    const int m0 = mt * 128;
    const int t = threadIdx.x, w = t >> 6, l = t & 63;
    const int srow = w * 8 + (l >> 3);
    const int skq  = l & 7;
    const bf16* Ab = Qt + (size_t)bh * 65536;
    const bf16* Bb = T  + (size_t)bh * 4096;
    #pragma unroll
    for (int c = 0; c < 4; ++c) {
        const int row = c * 32 + srow;
        const int gq = (skq ^ (row & 7)) * 8;
        gld_lds16(Ab + (size_t)(m0 + row) * 64 + gq, As + row * 64 + skq * 8);
    }
    #pragma unroll
    for (int c = 0; c < 2; ++c) {
        const int row = c * 32 + srow;
        const int gq = (skq ^ (row & 7)) * 8;
        gld_lds16(Bb + (size_t)row * 64 + gq, Bs + row * 64 + skq * 8);
    }
    __syncthreads();
    const int lm = l & 15, lq = l >> 4;
    const int wm = w * 32;
    f32x4 acc[2][4] = {};
    #pragma unroll
    for (int ks = 0; ks < 2; ++ks) {
        bf16x8 af[2], bfr[4];
        #pragma unroll
        for (int i = 0; i < 2; ++i) {
            const int row = wm + i * 16 + lm;
            const int qg = ks * 4 + lq;
            af[i] = *(const bf16x8*)(As + row * 64 + (qg ^ (row & 7)) * 8);
        }
        #pragma unroll
        for (int j = 0; j < 4; ++j) {
            const int row = j * 16 + lm;
            const int qg = ks * 4 + lq;
            bfr[j] = *(const bf16x8*)(Bs + row * 64 + (qg ^ (row & 7)) * 8);
        }
        #pragma unroll
        for (int i = 0; i < 2; ++i)
            #pragma unroll
            for (int j = 0; j < 4; ++j)
                acc[i][j] = __builtin_amdgcn_mfma_f32_16x16x32_bf16(af[i], bfr[j], acc[i][j], 0, 0, 0);
    }
    #pragma unroll
    for (int i = 0; i < 2; ++i)
        #pragma unroll
        for (int j = 0; j < 4; ++j)
            #pragma unroll
            for (int r = 0; r < 4; ++r) {
                const int lrow = m0 + wm + i * 16 + lq * 4 + r;
                const int col  = h * 64 + j * 16 + lm;
                mergedT[(size_t)b * 524288 + (size_t)lrow * 512 + col] = (bf16)acc[i][j][r];
            }
}

// ------------- InstanceNorm over L + gamma residual + LeakyReLU --------------
__global__ __launch_bounds__(256) void norm_kernel(
    const float* __restrict__ o, const float* __restrict__ x,
    const float* __restrict__ gamma, float* __restrict__ y)
{
    const size_t row = blockIdx.x;
    const float* orow = o + row * 1024;
    const float* xrow = x + row * 1024;
    float* yrow = y + row * 1024;
    const int tid = threadIdx.x;

    float4 v = ((const float4*)orow)[tid];
    float s  = v.x + v.y + v.z + v.w;
    float ss = v.x * v.x + v.y * v.y + v.z * v.z + v.w * v.w;
    #pragma unroll
    for (int off = 32; off > 0; off >>= 1) {
        s  += __shfl_down(s, off);
        ss += __shfl_down(ss, off);
    }
    __shared__ float red[10];
    const int wave = tid >> 6, lane = tid & 63;
    if (lane == 0) { red[wave] = s; red[4 + wave] = ss; }
    __syncthreads();
    if (tid == 0) {
        float a  = red[0] + red[1] + red[2] + red[3];
        float b2 = red[4] + red[5] + red[6] + red[7];
        float mu = a * (1.0f / 1024.0f);
        float var = b2 * (1.0f / 1024.0f) - mu * mu;
        red[8] = mu;
        red[9] = rsqrtf(var + EPS);
    }
    __syncthreads();
    const float mu = red[8], inv = red[9], g = gamma[0];
    float4 xv = ((const float4*)xrow)[tid];
    float4 r;
    r.x = (v.x - mu) * inv * g + xv.x;
    r.y = (v.y - mu) * inv * g + xv.y;
    r.z = (v.z - mu) * inv * g + xv.z;
    r.w = (v.w - mu) * inv * g + xv.w;
    r.x = r.x >= 0.f ? r.x : SLOPE * r.x;
    r.y = r.y >= 0.f ? r.y : SLOPE * r.y;
    r.z = r.z >= 0.f ? r.z : SLOPE * r.z;
    r.w = r.w >= 0.f ? r.w : SLOPE * r.w;
    ((float4*)yrow)[tid] = r;
}

extern "C" void kernel_launch(void* const* d_in, const int* in_sizes, int n_in,
                              void* d_out, int out_size, void* d_ws, size_t ws_size,
                              hipStream_t stream) {
    const float* x     = (const float*)d_in[0];   // [16,256,1024]
    const float* Wq    = (const float*)d_in[1];   // [512,256]
    const float* Wk    = (const float*)d_in[2];
    const float* Wv    = (const float*)d_in[3];
    const float* Wo    = (const float*)d_in[4];   // [256,512]
    const float* gamma = (const float*)d_in[5];
    float* y = (float*)d_out;

    char* wsb = (char*)d_ws;
    bf16*  xT   = (bf16*)(wsb);                   //  8,388,608 B
    bf16*  Wqkv = (bf16*)(wsb + 8388608);         //    786,432 B
    bf16*  WoB  = (bf16*)(wsb + 9175040);         //    262,144 B
    bf16*  QKV  = (bf16*)(wsb + 9437184);         // 50,331,648 B
    float* o    = (float*)(wsb + 9437184);        // aliases QKV (dead by then)
    bf16*  Qt   = (bf16*)(wsb + 59768832);        // 16,777,216 B
    bf16*  T    = (bf16*)(wsb + 76546048);        //  1,048,576 B
    bf16*  mT   = (bf16*)(wsb + 77594624);        // 16,777,216 B  (end 94,371,840)

    prep_x<<<dim3(16, 4, 16), 256, 0, stream>>>(x, xT);
    prep_w<<<dim3(512), 256, 0, stream>>>(Wq, Wk, Wv, Wo, Wqkv, WoB);

    // QKV = Wqkv * x  (per batch), output bf16 [b][1536][1024]
    gemm128_bt<256, bf16><<<dim3(12, 8, 16), 256, 0, stream>>>(
        Wqkv, xT, QKV, 262144LL, 1572864LL, 1024);

    transpose_q<<<dim3(16, 128), 256, 0, stream>>>(QKV, Qt);
    gemm_kvt<<<dim3(128), 256, 0, stream>>>(QKV, T);
    gemm_merged<<<dim3(8, 128), 256, 0, stream>>>(Qt, T, mT);

    // o = Wo * merged (per batch), fp32 out [b][256][1024]
    gemm128_bt<512, float><<<dim3(2, 8, 16), 256, 0, stream>>>(
        WoB, mT, o, 524288LL, 262144LL, 1024);

    norm_kernel<<<dim3(4096), 256, 0, stream>>>(o, x, gamma, y);
}

// Round 3
// 139.414 us; speedup vs baseline: 2.5871x; 1.0949x over previous
//
#include <hip/hip_runtime.h>

typedef __bf16 bf16;
typedef bf16 bf16x8 __attribute__((ext_vector_type(8)));
typedef bf16 bf16x4 __attribute__((ext_vector_type(4)));
typedef float f32x4 __attribute__((ext_vector_type(4)));

#define EPS 1e-5f
#define SLOPE 0.01f

// async global->LDS, 16B/lane. Invariant: lds ptr == wave base + lane*16B.
__device__ __forceinline__ void gld_lds16(const bf16* g, bf16* l) {
    __builtin_amdgcn_global_load_lds(
        (const __attribute__((address_space(1))) unsigned int*)g,
        (__attribute__((address_space(3))) unsigned int*)l, 16, 0, 0);
}

// ---------- prep: xT[b][l][c] bf16, xB[b][c][l] bf16, weights -> bf16 --------
__global__ __launch_bounds__(256) void prep_kernel(
    const float* __restrict__ x,
    const float* __restrict__ Wq, const float* __restrict__ Wk,
    const float* __restrict__ Wv, const float* __restrict__ Wo,
    bf16* __restrict__ xT, bf16* __restrict__ xB,
    bf16* __restrict__ WkvB, bf16* __restrict__ WqB, bf16* __restrict__ WoB)
{
    __shared__ float tile[64][65];
    const int id = blockIdx.x;
    const int t = threadIdx.x;
    if (id < 1024) {
        const int lt = id & 15, ct = (id >> 4) & 3, b = id >> 6;
        {
            const int cl = t >> 2;            // 0..63 (c within tile)
            const int l4 = (t & 3) << 4;      // 0,16,32,48
            const float* src = x + (size_t)(b * 256 + ct * 64 + cl) * 1024 + lt * 64 + l4;
            float4 v0 = ((const float4*)src)[0];
            float4 v1 = ((const float4*)src)[1];
            float4 v2 = ((const float4*)src)[2];
            float4 v3 = ((const float4*)src)[3];
            // xB: straight cast, same layout as x
            bf16x8 r0, r1;
            r0[0]=(bf16)v0.x; r0[1]=(bf16)v0.y; r0[2]=(bf16)v0.z; r0[3]=(bf16)v0.w;
            r0[4]=(bf16)v1.x; r0[5]=(bf16)v1.y; r0[6]=(bf16)v1.z; r0[7]=(bf16)v1.w;
            r1[0]=(bf16)v2.x; r1[1]=(bf16)v2.y; r1[2]=(bf16)v2.z; r1[3]=(bf16)v2.w;
            r1[4]=(bf16)v3.x; r1[5]=(bf16)v3.y; r1[6]=(bf16)v3.z; r1[7]=(bf16)v3.w;
            bf16* xbd = xB + (size_t)(b * 256 + ct * 64 + cl) * 1024 + lt * 64 + l4;
            *(bf16x8*)xbd = r0;
            *(bf16x8*)(xbd + 8) = r1;
            float* tr = &tile[cl][l4];
            tr[0]=v0.x; tr[1]=v0.y; tr[2]=v0.z; tr[3]=v0.w;
            tr[4]=v1.x; tr[5]=v1.y; tr[6]=v1.z; tr[7]=v1.w;
            tr[8]=v2.x; tr[9]=v2.y; tr[10]=v2.z; tr[11]=v2.w;
            tr[12]=v3.x; tr[13]=v3.y; tr[14]=v3.z; tr[15]=v3.w;
        }
        __syncthreads();
        {
            const int lw = t >> 2;            // l within tile
            const int ec = (t & 3) << 4;      // c within tile
            bf16x8 o0, o1;
            #pragma unroll
            for (int ii = 0; ii < 8; ++ii) {
                o0[ii] = (bf16)tile[ec + ii][lw];
                o1[ii] = (bf16)tile[ec + 8 + ii][lw];
            }
            bf16* dst = xT + (size_t)(b * 1024 + lt * 64 + lw) * 256 + ct * 64 + ec;
            *(bf16x8*)dst = o0;
            *(bf16x8*)(dst + 8) = o1;
        }
    } else {
        const int i = (id - 1024) * 1024 + t * 4;   // 0..524284
        const float* src; bf16* dst;
        if (i < 131072)      { src = Wk + i;            dst = WkvB + i; }
        else if (i < 262144) { src = Wv + (i - 131072); dst = WkvB + i; }
        else if (i < 393216) { src = Wq + (i - 262144); dst = WqB + (i - 262144); }
        else                 { src = Wo + (i - 393216); dst = WoB + (i - 393216); }
        float4 v = *(const float4*)src;
        bf16x4 o;
        o[0]=(bf16)v.x; o[1]=(bf16)v.y; o[2]=(bf16)v.z; o[3]=(bf16)v.w;
        *(bf16x4*)dst = o;
    }
}

// ---- combined projection GEMM (K=256, 128x128 tiles, B^T form, bf16 out) ----
// blocks [0,1024): KV[b] = WkvB * xT[b]^T   (M=1024,N=1024)
// blocks [1024,1536): Qt[b] = xT[b] * WqB^T (M=1024,N=512)
__global__ __launch_bounds__(256) void qkv_gemm(
    const bf16* __restrict__ WkvB, const bf16* __restrict__ WqB,
    const bf16* __restrict__ xT, bf16* __restrict__ KV, bf16* __restrict__ Qt)
{
    __shared__ bf16 As[128 * 32];
    __shared__ bf16 Bs[128 * 32];
    int id = blockIdx.x;
    const bf16 *A, *Bt; bf16* C; int ldc, m0, n0;
    if (id < 1024) {
        const int z = id >> 6, rem = id & 63;
        m0 = (rem >> 3) * 128; n0 = (rem & 7) * 128;
        A = WkvB; Bt = xT + (size_t)z * 262144;
        C = KV + (size_t)z * 1048576; ldc = 1024;
    } else {
        id -= 1024;
        const int z = id >> 5, rem = id & 31;
        m0 = (rem >> 2) * 128; n0 = (rem & 3) * 128;
        A = xT + (size_t)z * 262144; Bt = WqB;
        C = Qt + (size_t)z * 524288; ldc = 512;
    }
    const int t = threadIdx.x, w = t >> 6, l = t & 63;
    const int srow = w * 16 + (l >> 2);
    const int ske  = (l & 3) * 8;
    const bf16* ga = A  + (size_t)(m0 + srow) * 256 + ske;
    const bf16* gb = Bt + (size_t)(n0 + srow) * 256 + ske;
    bf16* la = As + srow * 32 + ske;
    bf16* lb = Bs + srow * 32 + ske;
    const int lm = l & 15, lq = l >> 4;
    const int wm = (w & 1) * 64, wn = (w >> 1) * 64;

    f32x4 acc[4][4] = {};
    for (int kt = 0; kt < 8; ++kt) {
        const int k0 = kt * 32;
        gld_lds16(ga + k0, la);
        gld_lds16(ga + k0 + (size_t)64 * 256, la + 64 * 32);
        gld_lds16(gb + k0, lb);
        gld_lds16(gb + k0 + (size_t)64 * 256, lb + 64 * 32);
        __syncthreads();
        bf16x8 af[4], bfr[4];
        #pragma unroll
        for (int i = 0; i < 4; ++i)
            af[i] = *(const bf16x8*)(As + (wm + i * 16 + lm) * 32 + lq * 8);
        #pragma unroll
        for (int j = 0; j < 4; ++j)
            bfr[j] = *(const bf16x8*)(Bs + (wn + j * 16 + lm) * 32 + lq * 8);
        #pragma unroll
        for (int i = 0; i < 4; ++i)
            #pragma unroll
            for (int j = 0; j < 4; ++j)
                acc[i][j] = __builtin_amdgcn_mfma_f32_16x16x32_bf16(af[i], bfr[j], acc[i][j], 0, 0, 0);
        __syncthreads();
    }
    #pragma unroll
    for (int i = 0; i < 4; ++i)
        #pragma unroll
        for (int j = 0; j < 4; ++j) {
            const int row = m0 + wm + i * 16 + lq * 4;
            const int col = n0 + wn + j * 16 + lm;
            bf16* cp = C + (size_t)row * ldc + col;
            #pragma unroll
            for (int r = 0; r < 4; ++r)
                cp[(size_t)r * ldc] = (bf16)acc[i][j][r];
        }
}

// ------- 128x128-tile MFMA GEMM, B^T form (for Wo): C[z] = A * Bt[z]^T -------
template<int KDIM, typename OutT>
__global__ __launch_bounds__(256) void gemm128_bt(
    const bf16* __restrict__ A, const bf16* __restrict__ Bt, OutT* __restrict__ C,
    long long sBt, long long sC, int ldC)
{
    __shared__ bf16 As[128 * 32];
    __shared__ bf16 Bs[128 * 32];
    const int z = blockIdx.z;
    Bt += (size_t)z * sBt;
    C  += (size_t)z * sC;
    const int m0 = blockIdx.x * 128;
    const int n0 = blockIdx.y * 128;
    const int t = threadIdx.x, w = t >> 6, l = t & 63;
    const int srow = w * 16 + (l >> 2);
    const int ske  = (l & 3) * 8;
    const bf16* ga = A  + (size_t)(m0 + srow) * KDIM + ske;
    const bf16* gb = Bt + (size_t)(n0 + srow) * KDIM + ske;
    bf16* la = As + srow * 32 + ske;
    bf16* lb = Bs + srow * 32 + ske;
    const int lm = l & 15, lq = l >> 4;
    const int wm = (w & 1) * 64, wn = (w >> 1) * 64;

    f32x4 acc[4][4] = {};
    for (int kt = 0; kt < KDIM / 32; ++kt) {
        const int k0 = kt * 32;
        gld_lds16(ga + k0, la);
        gld_lds16(ga + k0 + (size_t)64 * KDIM, la + 64 * 32);
        gld_lds16(gb + k0, lb);
        gld_lds16(gb + k0 + (size_t)64 * KDIM, lb + 64 * 32);
        __syncthreads();
        bf16x8 af[4], bfr[4];
        #pragma unroll
        for (int i = 0; i < 4; ++i)
            af[i] = *(const bf16x8*)(As + (wm + i * 16 + lm) * 32 + lq * 8);
        #pragma unroll
        for (int j = 0; j < 4; ++j)
            bfr[j] = *(const bf16x8*)(Bs + (wn + j * 16 + lm) * 32 + lq * 8);
        #pragma unroll
        for (int i = 0; i < 4; ++i)
            #pragma unroll
            for (int j = 0; j < 4; ++j)
                acc[i][j] = __builtin_amdgcn_mfma_f32_16x16x32_bf16(af[i], bfr[j], acc[i][j], 0, 0, 0);
        __syncthreads();
    }
    #pragma unroll
    for (int i = 0; i < 4; ++i)
        #pragma unroll
        for (int j = 0; j < 4; ++j) {
            const int row = m0 + wm + i * 16 + lq * 4;
            const int col = n0 + wn + j * 16 + lm;
            OutT* cp = C + (size_t)row * ldC + col;
            #pragma unroll
            for (int r = 0; r < 4; ++r)
                cp[(size_t)r * ldC] = (OutT)acc[i][j][r];
        }
}

// ---- kvT: T[bh][d][e] = (1/64) sum_l V[d,l]*K[e,l], 4 mega-stages of K=256 --
__global__ __launch_bounds__(256) void kvt_kernel(const bf16* __restrict__ KV,
                                                  bf16* __restrict__ T)
{
    __shared__ bf16 As[64 * 256];   // V rows, swizzled 16B segments
    __shared__ bf16 Bs[64 * 256];   // K rows
    const int bh = blockIdx.x;
    const int b = bh >> 3, h = bh & 7;
    const bf16* Kb = KV + (size_t)b * 1048576 + (size_t)(h * 64) * 1024;
    const bf16* Vb = KV + (size_t)b * 1048576 + (size_t)(512 + h * 64) * 1024;
    const int t = threadIdx.x, w = t >> 6, l = t & 63;
    const int lm = l & 15, lq = l >> 4;
    const int wm = (w & 1) * 32, wn = (w >> 1) * 32;
    const int lrow = l >> 5;        // 0/1: which of the 2 rows this lane stages
    const int lseg = l & 31;        // 16B segment within row

    f32x4 acc[2][2] = {};
    for (int st = 0; st < 4; ++st) {
        const int k0 = st * 256;
        #pragma unroll
        for (int r = 0; r < 8; ++r) {
            const int row = w * 16 + r * 2 + lrow;
            const int gs = lseg ^ (row & 7);
            gld_lds16(Vb + (size_t)row * 1024 + k0 + gs * 8, As + row * 256 + lseg * 8);
            gld_lds16(Kb + (size_t)row * 1024 + k0 + gs * 8, Bs + row * 256 + lseg * 8);
        }
        __syncthreads();
        #pragma unroll
        for (int kc = 0; kc < 8; ++kc) {
            const int q = kc * 4 + lq;
            bf16x8 af[2], bfr[2];
            #pragma unroll
            for (int i = 0; i < 2; ++i) {
                const int m = wm + i * 16 + lm;
                af[i] = *(const bf16x8*)(As + m * 256 + (q ^ (m & 7)) * 8);
            }
            #pragma unroll
            for (int j = 0; j < 2; ++j) {
                const int n = wn + j * 16 + lm;
                bfr[j] = *(const bf16x8*)(Bs + n * 256 + (q ^ (n & 7)) * 8);
            }
            #pragma unroll
            for (int i = 0; i < 2; ++i)
                #pragma unroll
                for (int j = 0; j < 2; ++j)
                    acc[i][j] = __builtin_amdgcn_mfma_f32_16x16x32_bf16(af[i], bfr[j], acc[i][j], 0, 0, 0);
        }
        if (st < 3) __syncthreads();
    }
    #pragma unroll
    for (int i = 0; i < 2; ++i)
        #pragma unroll
        for (int j = 0; j < 2; ++j)
            #pragma unroll
            for (int r = 0; r < 4; ++r)
                T[(size_t)bh * 4096 + (size_t)(wm + i * 16 + lq * 4 + r) * 64 + wn + j * 16 + lm] =
                    (bf16)(acc[i][j][r] * 0.015625f);
}

// -- mergedT[b][l][h*64+d] = sum_e Qt[b][l][h*64+e] * T[bh][d][e] (K=64) ------
__global__ __launch_bounds__(256) void gemm_merged(const bf16* __restrict__ Qt,
                                                   const bf16* __restrict__ T,
                                                   bf16* __restrict__ mT)
{
    __shared__ bf16 As[128 * 64];
    __shared__ bf16 Bs[64 * 64];
    const int mt = blockIdx.x;   // 0..7 (l-tile)
    const int bh = blockIdx.y;   // 0..127
    const int b = bh >> 3, h = bh & 7;
    const int m0 = mt * 128;
    const int t = threadIdx.x, w = t >> 6, l = t & 63;
    const bf16* Ab = Qt + (size_t)b * 524288 + h * 64;
    const bf16* Bb = T  + (size_t)bh * 4096;
    const int lr = l >> 3;     // 0..7 row within 8-row group
    const int ls = l & 7;      // 16B segment within 64-elem row
    #pragma unroll
    for (int c = 0; c < 4; ++c) {
        const int row = c * 32 + w * 8 + lr;
        const int gs = ls ^ (row & 7);
        gld_lds16(Ab + (size_t)(m0 + row) * 512 + gs * 8, As + row * 64 + ls * 8);
    }
    #pragma unroll
    for (int c = 0; c < 2; ++c) {
        const int row = c * 32 + w * 8 + lr;
        const int gs = ls ^ (row & 7);
        gld_lds16(Bb + (size_t)row * 64 + gs * 8, Bs + row * 64 + ls * 8);
    }
    __syncthreads();
    const int lm = l & 15, lq = l >> 4;
    const int wm = w * 32;
    f32x4 acc[2][4] = {};
    #pragma unroll
    for (int ks = 0; ks < 2; ++ks) {
        const int q = ks * 4 + lq;
        bf16x8 af[2], bfr[4];
        #pragma unroll
        for (int i = 0; i < 2; ++i) {
            const int m = wm + i * 16 + lm;
            af[i] = *(const bf16x8*)(As + m * 64 + (q ^ (m & 7)) * 8);
        }
        #pragma unroll
        for (int j = 0; j < 4; ++j) {
            const int n = j * 16 + lm;
            bfr[j] = *(const bf16x8*)(Bs + n * 64 + (q ^ (n & 7)) * 8);
        }
        #pragma unroll
        for (int i = 0; i < 2; ++i)
            #pragma unroll
            for (int j = 0; j < 4; ++j)
                acc[i][j] = __builtin_amdgcn_mfma_f32_16x16x32_bf16(af[i], bfr[j], acc[i][j], 0, 0, 0);
    }
    #pragma unroll
    for (int i = 0; i < 2; ++i)
        #pragma unroll
        for (int j = 0; j < 4; ++j)
            #pragma unroll
            for (int r = 0; r < 4; ++r) {
                const int lrow = m0 + wm + i * 16 + lq * 4 + r;
                const int col  = h * 64 + j * 16 + lm;
                mT[(size_t)b * 524288 + (size_t)lrow * 512 + col] = (bf16)acc[i][j][r];
            }
}

// ------------- InstanceNorm over L + gamma residual + LeakyReLU --------------
__global__ __launch_bounds__(256) void norm_kernel(
    const bf16* __restrict__ o, const bf16* __restrict__ xB,
    const float* __restrict__ gamma, float* __restrict__ y)
{
    const size_t row = blockIdx.x;
    const bf16* orow = o + row * 1024;
    const bf16* xrow = xB + row * 1024;
    float* yrow = y + row * 1024;
    const int tid = threadIdx.x;

    bf16x4 ov = *(const bf16x4*)(orow + tid * 4);
    float4 v = {(float)ov[0], (float)ov[1], (float)ov[2], (float)ov[3]};
    float s  = v.x + v.y + v.z + v.w;
    float ss = v.x * v.x + v.y * v.y + v.z * v.z + v.w * v.w;
    #pragma unroll
    for (int off = 32; off > 0; off >>= 1) {
        s  += __shfl_down(s, off);
        ss += __shfl_down(ss, off);
    }
    __shared__ float red[10];
    const int wave = tid >> 6, lane = tid & 63;
    if (lane == 0) { red[wave] = s; red[4 + wave] = ss; }
    __syncthreads();
    if (tid == 0) {
        float a  = red[0] + red[1] + red[2] + red[3];
        float b2 = red[4] + red[5] + red[6] + red[7];
        float mu = a * (1.0f / 1024.0f);
        float var = b2 * (1.0f / 1024.0f) - mu * mu;
        red[8] = mu;
        red[9] = rsqrtf(var + EPS);
    }
    __syncthreads();
    const float mu = red[8], inv = red[9], g = gamma[0];
    bf16x4 xv4 = *(const bf16x4*)(xrow + tid * 4);
    float4 r;
    r.x = (v.x - mu) * inv * g + (float)xv4[0];
    r.y = (v.y - mu) * inv * g + (float)xv4[1];
    r.z = (v.z - mu) * inv * g + (float)xv4[2];
    r.w = (v.w - mu) * inv * g + (float)xv4[3];
    r.x = r.x >= 0.f ? r.x : SLOPE * r.x;
    r.y = r.y >= 0.f ? r.y : SLOPE * r.y;
    r.z = r.z >= 0.f ? r.z : SLOPE * r.z;
    r.w = r.w >= 0.f ? r.w : SLOPE * r.w;
    ((float4*)yrow)[tid] = r;
}

extern "C" void kernel_launch(void* const* d_in, const int* in_sizes, int n_in,
                              void* d_out, int out_size, void* d_ws, size_t ws_size,
                              hipStream_t stream) {
    const float* x     = (const float*)d_in[0];
    const float* Wq    = (const float*)d_in[1];
    const float* Wk    = (const float*)d_in[2];
    const float* Wv    = (const float*)d_in[3];
    const float* Wo    = (const float*)d_in[4];
    const float* gamma = (const float*)d_in[5];
    float* y = (float*)d_out;

    char* wsb = (char*)d_ws;
    bf16* xT   = (bf16*)(wsb);                  //  8,388,608 B
    bf16* xB   = (bf16*)(wsb +  8388608);       //  8,388,608 B
    bf16* WkvB = (bf16*)(wsb + 16777216);       //    524,288 B
    bf16* WqB  = (bf16*)(wsb + 17301504);       //    262,144 B
    bf16* WoB  = (bf16*)(wsb + 17563648);       //    262,144 B
    bf16* KV   = (bf16*)(wsb + 17825792);       // 33,554,432 B
    bf16* Qt   = (bf16*)(wsb + 51380224);       // 16,777,216 B
    bf16* T    = (bf16*)(wsb + 68157440);       //  1,048,576 B
    bf16* mT   = (bf16*)(wsb + 69206016);       // 16,777,216 B
    bf16* o    = (bf16*)(wsb + 85983232);       //  8,388,608 B  (end 94,371,840)

    prep_kernel<<<dim3(1536), 256, 0, stream>>>(x, Wq, Wk, Wv, Wo, xT, xB, WkvB, WqB, WoB);
    qkv_gemm<<<dim3(1536), 256, 0, stream>>>(WkvB, WqB, xT, KV, Qt);
    kvt_kernel<<<dim3(128), 256, 0, stream>>>(KV, T);
    gemm_merged<<<dim3(8, 128), 256, 0, stream>>>(Qt, T, mT);
    gemm128_bt<512, bf16><<<dim3(2, 8, 16), 256, 0, stream>>>(WoB, mT, o, 524288LL, 262144LL, 1024);
    norm_kernel<<<dim3(4096), 256, 0, stream>>>(o, xB, gamma, y);
}

// Round 4
// 139.026 us; speedup vs baseline: 2.5943x; 1.0028x over previous
//
#include <hip/hip_runtime.h>

typedef __bf16 bf16;
typedef bf16 bf16x8 __attribute__((ext_vector_type(8)));
typedef bf16 bf16x4 __attribute__((ext_vector_type(4)));
typedef float f32x4 __attribute__((ext_vector_type(4)));

#define EPS 1e-5f
#define SLOPE 0.01f

// async global->LDS, 16B/lane. Invariant: lds ptr == wave-uniform base + lane*16B.
__device__ __forceinline__ void gld_lds16(const bf16* g, bf16* l) {
    __builtin_amdgcn_global_load_lds(
        (const __attribute__((address_space(1))) unsigned int*)g,
        (__attribute__((address_space(3))) unsigned int*)l, 16, 0, 0);
}

// ---------- prep: xT[b][l][c], xB[b][c][l], Wk/Wv/Wo bf16, WqT[h][c][e] ------
__global__ __launch_bounds__(256) void prep_kernel(
    const float* __restrict__ x,
    const float* __restrict__ Wq, const float* __restrict__ Wk,
    const float* __restrict__ Wv, const float* __restrict__ Wo,
    bf16* __restrict__ xT, bf16* __restrict__ xB,
    bf16* __restrict__ WkB, bf16* __restrict__ WvB,
    bf16* __restrict__ WoB, bf16* __restrict__ WqT)
{
    __shared__ float tile[64][65];
    const int id = blockIdx.x;
    const int t = threadIdx.x;
    if (id < 1024) {
        const int lt = id & 15, ct = (id >> 4) & 3, b = id >> 6;
        {
            const int cl = t >> 2;            // c within tile
            const int l4 = (t & 3) << 4;      // l within tile (16-chunks)
            const float* src = x + (size_t)(b * 256 + ct * 64 + cl) * 1024 + lt * 64 + l4;
            float4 v0 = ((const float4*)src)[0];
            float4 v1 = ((const float4*)src)[1];
            float4 v2 = ((const float4*)src)[2];
            float4 v3 = ((const float4*)src)[3];
            bf16x8 r0, r1;
            r0[0]=(bf16)v0.x; r0[1]=(bf16)v0.y; r0[2]=(bf16)v0.z; r0[3]=(bf16)v0.w;
            r0[4]=(bf16)v1.x; r0[5]=(bf16)v1.y; r0[6]=(bf16)v1.z; r0[7]=(bf16)v1.w;
            r1[0]=(bf16)v2.x; r1[1]=(bf16)v2.y; r1[2]=(bf16)v2.z; r1[3]=(bf16)v2.w;
            r1[4]=(bf16)v3.x; r1[5]=(bf16)v3.y; r1[6]=(bf16)v3.z; r1[7]=(bf16)v3.w;
            bf16* xbd = xB + (size_t)(b * 256 + ct * 64 + cl) * 1024 + lt * 64 + l4;
            *(bf16x8*)xbd = r0;
            *(bf16x8*)(xbd + 8) = r1;
            float* tr = &tile[cl][l4];
            tr[0]=v0.x; tr[1]=v0.y; tr[2]=v0.z; tr[3]=v0.w;
            tr[4]=v1.x; tr[5]=v1.y; tr[6]=v1.z; tr[7]=v1.w;
            tr[8]=v2.x; tr[9]=v2.y; tr[10]=v2.z; tr[11]=v2.w;
            tr[12]=v3.x; tr[13]=v3.y; tr[14]=v3.z; tr[15]=v3.w;
        }
        __syncthreads();
        {
            const int lw = t >> 2;            // l within tile
            const int ec = (t & 3) << 4;      // c within tile
            bf16x8 o0, o1;
            #pragma unroll
            for (int ii = 0; ii < 8; ++ii) {
                o0[ii] = (bf16)tile[ec + ii][lw];
                o1[ii] = (bf16)tile[ec + 8 + ii][lw];
            }
            bf16* dst = xT + (size_t)(b * 1024 + lt * 64 + lw) * 256 + ct * 64 + ec;
            *(bf16x8*)dst = o0;
            *(bf16x8*)(dst + 8) = o1;
        }
    } else if (id < 1408) {
        // straight bf16 casts of Wk, Wv, Wo
        const int i = (id - 1024) * 1024 + t * 4;    // [0, 393216)
        const float* src; bf16* dst;
        if (i < 131072)      { src = Wk + i;            dst = WkB + i; }
        else if (i < 262144) { src = Wv + (i - 131072); dst = WvB + (i - 131072); }
        else                 { src = Wo + (i - 262144); dst = WoB + (i - 262144); }
        float4 v = *(const float4*)src;
        bf16x4 o;
        o[0]=(bf16)v.x; o[1]=(bf16)v.y; o[2]=(bf16)v.z; o[3]=(bf16)v.w;
        *(bf16x4*)dst = o;
    } else {
        // per-head transpose: WqT[h][c][e] = Wq[h*64+e][c]
        const int id2 = id - 1408;            // 0..31
        const int h = id2 >> 2, ct = id2 & 3;
        {
            const int e  = t >> 2;
            const int c4 = (t & 3) << 4;
            const float* src = Wq + (size_t)(h * 64 + e) * 256 + ct * 64 + c4;
            float4 v0 = ((const float4*)src)[0];
            float4 v1 = ((const float4*)src)[1];
            float4 v2 = ((const float4*)src)[2];
            float4 v3 = ((const float4*)src)[3];
            float* tr = &tile[e][c4];
            tr[0]=v0.x; tr[1]=v0.y; tr[2]=v0.z; tr[3]=v0.w;
            tr[4]=v1.x; tr[5]=v1.y; tr[6]=v1.z; tr[7]=v1.w;
            tr[8]=v2.x; tr[9]=v2.y; tr[10]=v2.z; tr[11]=v2.w;
            tr[12]=v3.x; tr[13]=v3.y; tr[14]=v3.z; tr[15]=v3.w;
        }
        __syncthreads();
        {
            const int c  = t >> 2;
            const int e4 = (t & 3) << 4;
            bf16x8 o0, o1;
            #pragma unroll
            for (int ii = 0; ii < 8; ++ii) {
                o0[ii] = (bf16)tile[e4 + ii][c];
                o1[ii] = (bf16)tile[e4 + 8 + ii][c];
            }
            bf16* dst = WqT + (size_t)h * 16384 + (size_t)(ct * 64 + c) * 64 + e4;
            *(bf16x8*)dst = o0;
            *(bf16x8*)(dst + 8) = o1;
        }
    }
}

// ------- 128x128-tile MFMA GEMM, B^T form: C[z] = A[z] * Bt[z]^T -------------
template<int KDIM, typename OutT>
__global__ __launch_bounds__(256) void gemm128_bt(
    const bf16* __restrict__ A, const bf16* __restrict__ Bt, OutT* __restrict__ C,
    long long sA, long long sBt, long long sC, int ldC)
{
    __shared__ bf16 As[128 * 32];
    __shared__ bf16 Bs[128 * 32];
    const int z = blockIdx.z;
    A  += (size_t)z * sA;
    Bt += (size_t)z * sBt;
    C  += (size_t)z * sC;
    const int m0 = blockIdx.x * 128;
    const int n0 = blockIdx.y * 128;
    const int t = threadIdx.x, w = t >> 6, l = t & 63;
    const int srow = w * 16 + (l >> 2);
    const int ske  = (l & 3) * 8;
    const bf16* ga = A  + (size_t)(m0 + srow) * KDIM + ske;
    const bf16* gb = Bt + (size_t)(n0 + srow) * KDIM + ske;
    bf16* la = As + srow * 32 + ske;
    bf16* lb = Bs + srow * 32 + ske;
    const int lm = l & 15, lq = l >> 4;
    const int wm = (w & 1) * 64, wn = (w >> 1) * 64;

    f32x4 acc[4][4] = {};
    for (int kt = 0; kt < KDIM / 32; ++kt) {
        const int k0 = kt * 32;
        gld_lds16(ga + k0, la);
        gld_lds16(ga + k0 + (size_t)64 * KDIM, la + 64 * 32);
        gld_lds16(gb + k0, lb);
        gld_lds16(gb + k0 + (size_t)64 * KDIM, lb + 64 * 32);
        __syncthreads();
        bf16x8 af[4], bfr[4];
        #pragma unroll
        for (int i = 0; i < 4; ++i)
            af[i] = *(const bf16x8*)(As + (wm + i * 16 + lm) * 32 + lq * 8);
        #pragma unroll
        for (int j = 0; j < 4; ++j)
            bfr[j] = *(const bf16x8*)(Bs + (wn + j * 16 + lm) * 32 + lq * 8);
        #pragma unroll
        for (int i = 0; i < 4; ++i)
            #pragma unroll
            for (int j = 0; j < 4; ++j)
                acc[i][j] = __builtin_amdgcn_mfma_f32_16x16x32_bf16(af[i], bfr[j], acc[i][j], 0, 0, 0);
        __syncthreads();
    }
    #pragma unroll
    for (int i = 0; i < 4; ++i)
        #pragma unroll
        for (int j = 0; j < 4; ++j) {
            const int row = m0 + wm + i * 16 + lq * 4;
            const int col = n0 + wn + j * 16 + lm;
            OutT* cp = C + (size_t)row * ldC + col;
            #pragma unroll
            for (int r = 0; r < 4; ++r)
                cp[(size_t)r * ldC] = (OutT)acc[i][j][r];
        }
}

// ---- per-(b,h): T_h = (1/64) S_h Wk_h^T  then  WmT_h = WqT_h (x) T_h --------
// S_h [64,256] (k=c'), Wk_h [64,256] (k=c'), WqT_h [256,64] (k=e), T_h [64,64].
// Output WmT[b][c][h*64+d].
__global__ __launch_bounds__(256) void tm_kernel(
    const bf16* __restrict__ S, const bf16* __restrict__ WkB,
    const bf16* __restrict__ WqT, bf16* __restrict__ WmT)
{
    __shared__ __align__(16) bf16 regA[16384];   // 32KB: S/K chunks, then T
    __shared__ __align__(16) bf16 Qb[16384];     // 32KB: WqT_h
    bf16* Sc = regA;            // [64][128] chunk
    bf16* Kc = regA + 8192;     // [64][128] chunk
    bf16* Tb = regA;            // [64][64] after phase T

    const int bh = blockIdx.x;
    const int b = bh >> 3, h = bh & 7;
    const bf16* Sg = S   + (size_t)b * 131072 + (size_t)h * 64 * 256;
    const bf16* Kg = WkB + (size_t)h * 64 * 256;
    const bf16* Qg = WqT + (size_t)h * 16384;
    const int t = threadIdx.x, w = t >> 6, l = t & 63;
    const int lm = l & 15, lq = l >> 4;

    // stage WqT_h: 256 rows x 8 segs, swizzle s^(r&7)
    #pragma unroll
    for (int it = 0; it < 8; ++it) {
        const int idx = it * 256 + t;
        const int r = idx >> 3, s = idx & 7;
        gld_lds16(Qg + (size_t)r * 64 + (s ^ (r & 7)) * 8, Qb + r * 64 + s * 8);
    }

    f32x4 accT[4] = {};
    for (int ck = 0; ck < 2; ++ck) {
        const int k0 = ck * 128;
        #pragma unroll
        for (int it = 0; it < 4; ++it) {
            const int idx = it * 256 + t;
            const int r = idx >> 4, s = idx & 15;
            const int gs = (s ^ (r & 7)) * 8;
            gld_lds16(Sg + (size_t)r * 256 + k0 + gs, Sc + r * 128 + s * 8);
            gld_lds16(Kg + (size_t)r * 256 + k0 + gs, Kc + r * 128 + s * 8);
        }
        __syncthreads();
        #pragma unroll
        for (int ks = 0; ks < 4; ++ks) {
            const int q = ks * 4 + lq;                 // 0..15
            const int ra = w * 16 + lm;
            bf16x8 a = *(const bf16x8*)(Sc + ra * 128 + (q ^ (ra & 7)) * 8);
            #pragma unroll
            for (int nf = 0; nf < 4; ++nf) {
                const int rb = nf * 16 + lm;
                bf16x8 bb = *(const bf16x8*)(Kc + rb * 128 + (q ^ (rb & 7)) * 8);
                accT[nf] = __builtin_amdgcn_mfma_f32_16x16x32_bf16(a, bb, accT[nf], 0, 0, 0);
            }
        }
        __syncthreads();
    }
    // write T (scaled) into regA, swizzled [64][64], 8 segs/row
    #pragma unroll
    for (int nf = 0; nf < 4; ++nf)
        #pragma unroll
        for (int ri = 0; ri < 4; ++ri) {
            const int row = w * 16 + lq * 4 + ri;
            const int col = nf * 16 + lm;
            Tb[row * 64 + (((col >> 3) ^ (row & 7)) << 3) + (col & 7)] =
                (bf16)(accT[nf][ri] * 0.015625f);
        }
    __syncthreads();

    // phase M: WmT_h[c,d] = sum_e WqT_h[c,e] T_h[d,e], M=256 N=64 K=64
    f32x4 accM[4][4] = {};
    #pragma unroll
    for (int ks = 0; ks < 2; ++ks) {
        const int q = ks * 4 + lq;                     // 0..7
        bf16x8 bfrag[4];
        #pragma unroll
        for (int nf = 0; nf < 4; ++nf) {
            const int rb = nf * 16 + lm;
            bfrag[nf] = *(const bf16x8*)(Tb + rb * 64 + (q ^ (rb & 7)) * 8);
        }
        #pragma unroll
        for (int mf = 0; mf < 4; ++mf) {
            const int ra = w * 64 + mf * 16 + lm;
            bf16x8 a = *(const bf16x8*)(Qb + ra * 64 + (q ^ (ra & 7)) * 8);
            #pragma unroll
            for (int nf = 0; nf < 4; ++nf)
                accM[mf][nf] = __builtin_amdgcn_mfma_f32_16x16x32_bf16(a, bfrag[nf], accM[mf][nf], 0, 0, 0);
        }
    }
    bf16* Wg = WmT + (size_t)b * 131072 + h * 64;
    #pragma unroll
    for (int mf = 0; mf < 4; ++mf)
        #pragma unroll
        for (int nf = 0; nf < 4; ++nf)
            #pragma unroll
            for (int ri = 0; ri < 4; ++ri) {
                const int c = w * 64 + mf * 16 + lq * 4 + ri;
                const int d = nf * 16 + lm;
                Wg[(size_t)c * 512 + d] = (bf16)accM[mf][nf][ri];
            }
}

// ------------- InstanceNorm over L + gamma residual + LeakyReLU --------------
__global__ __launch_bounds__(256) void norm_kernel(
    const bf16* __restrict__ o, const bf16* __restrict__ xB,
    const float* __restrict__ gamma, float* __restrict__ y)
{
    const size_t row = blockIdx.x;
    const bf16* orow = o + row * 1024;
    const bf16* xrow = xB + row * 1024;
    float* yrow = y + row * 1024;
    const int tid = threadIdx.x;

    bf16x4 ov = *(const bf16x4*)(orow + tid * 4);
    float4 v = {(float)ov[0], (float)ov[1], (float)ov[2], (float)ov[3]};
    float s  = v.x + v.y + v.z + v.w;
    float ss = v.x * v.x + v.y * v.y + v.z * v.z + v.w * v.w;
    #pragma unroll
    for (int off = 32; off > 0; off >>= 1) {
        s  += __shfl_down(s, off);
        ss += __shfl_down(ss, off);
    }
    __shared__ float red[10];
    const int wave = tid >> 6, lane = tid & 63;
    if (lane == 0) { red[wave] = s; red[4 + wave] = ss; }
    __syncthreads();
    if (tid == 0) {
        float a  = red[0] + red[1] + red[2] + red[3];
        float b2 = red[4] + red[5] + red[6] + red[7];
        float mu = a * (1.0f / 1024.0f);
        float var = b2 * (1.0f / 1024.0f) - mu * mu;
        red[8] = mu;
        red[9] = rsqrtf(var + EPS);
    }
    __syncthreads();
    const float mu = red[8], inv = red[9], g = gamma[0];
    bf16x4 xv4 = *(const bf16x4*)(xrow + tid * 4);
    float4 r;
    r.x = (v.x - mu) * inv * g + (float)xv4[0];
    r.y = (v.y - mu) * inv * g + (float)xv4[1];
    r.z = (v.z - mu) * inv * g + (float)xv4[2];
    r.w = (v.w - mu) * inv * g + (float)xv4[3];
    r.x = r.x >= 0.f ? r.x : SLOPE * r.x;
    r.y = r.y >= 0.f ? r.y : SLOPE * r.y;
    r.z = r.z >= 0.f ? r.z : SLOPE * r.z;
    r.w = r.w >= 0.f ? r.w : SLOPE * r.w;
    ((float4*)yrow)[tid] = r;
}

extern "C" void kernel_launch(void* const* d_in, const int* in_sizes, int n_in,
                              void* d_out, int out_size, void* d_ws, size_t ws_size,
                              hipStream_t stream) {
    const float* x     = (const float*)d_in[0];
    const float* Wq    = (const float*)d_in[1];
    const float* Wk    = (const float*)d_in[2];
    const float* Wv    = (const float*)d_in[3];
    const float* Wo    = (const float*)d_in[4];
    const float* gamma = (const float*)d_in[5];
    float* y = (float*)d_out;

    char* wsb = (char*)d_ws;
    bf16* xT  = (bf16*)(wsb);                   //  8,388,608
    bf16* xB  = (bf16*)(wsb +  8388608);        //  8,388,608
    bf16* WkB = (bf16*)(wsb + 16777216);        //    262,144
    bf16* WvB = (bf16*)(wsb + 17039360);        //    262,144
    bf16* WoB = (bf16*)(wsb + 17301504);        //    262,144
    bf16* WqT = (bf16*)(wsb + 17563648);        //    262,144
    bf16* G   = (bf16*)(wsb + 17825792);        //  2,097,152
    bf16* S   = (bf16*)(wsb + 19922944);        //  4,194,304
    bf16* WmT = (bf16*)(wsb + 24117248);        //  4,194,304
    bf16* Wt  = (bf16*)(wsb + 28311552);        //  2,097,152
    bf16* o   = (bf16*)(wsb + 30408704);        //  8,388,608  (end 38,797,312)

    prep_kernel<<<dim3(1440), 256, 0, stream>>>(x, Wq, Wk, Wv, Wo, xT, xB, WkB, WvB, WoB, WqT);

    // G[b] = xB[b] (x) xB[b]  : [256,256], K=1024 (symmetric Gram)
    gemm128_bt<1024, bf16><<<dim3(2, 2, 16), 256, 0, stream>>>(
        xB, xB, G, 262144LL, 262144LL, 65536LL, 256);

    // S[b] = WvB (x) G[b] : [512,256], K=256
    gemm128_bt<256, bf16><<<dim3(4, 2, 16), 256, 0, stream>>>(
        WvB, G, S, 0LL, 65536LL, 131072LL, 256);

    // T_h = (1/64) S_h Wk_h^T ; WmT[b][c][hd] = sum_e Wq_h[e,c] T_h[d,e]
    tm_kernel<<<dim3(128), 256, 0, stream>>>(S, WkB, WqT, WmT);

    // Wt[b] = WoB (x) WmT[b] : [256,256], K=512
    gemm128_bt<512, bf16><<<dim3(2, 2, 16), 256, 0, stream>>>(
        WoB, WmT, Wt, 0LL, 131072LL, 65536LL, 256);

    // o[b] = Wt[b] (x) xT[b] : [256,1024], K=256
    gemm128_bt<256, bf16><<<dim3(2, 8, 16), 256, 0, stream>>>(
        Wt, xT, o, 65536LL, 262144LL, 262144LL, 1024);

    norm_kernel<<<dim3(4096), 256, 0, stream>>>(o, xB, gamma, y);
}